// Round 4
// baseline (126.345 us; speedup 1.0000x reference)
//
#include <hip/hip_runtime.h>
#include <math.h>

// CompressedAttention: B=4,S=4096,H=2,KVH=1,D=2,MD=5
// scores_ij = al_{h,i}*P_j + be_{h,i}*Q_j (rank-2); v colinear -> scalar out weight.
// R4: RPT=8 rows/thread (halves L2 traffic vs R3), heads packed as float2 to get
// v_pk_fma_f32, wave-owned rows + shfl_xor reduction (zero LDS), analytic shift.

#define BQ 4
#define SQ 4096
#define MDQ 5
#define EPSQ 1e-6f
#define SCALEQ 16.0f
#define L2E 1.4426950408889634f
#define ISQ2 0.70710678118654752f

__device__ __forceinline__ float fast_exp2(float x) {
#if __has_builtin(__builtin_amdgcn_exp2f)
    return __builtin_amdgcn_exp2f(x);
#else
    return __expf(x * 0.6931471805599453f);
#endif
}

// ---------------- pre-pass: per-key scalars (P,Q,Cv) ----------------
__global__ __launch_bounds__(256)
void ca_prep(const float* __restrict__ x, const float* __restrict__ freqs,
             const float* __restrict__ qk_v, const float* __restrict__ v_v,
             const float* __restrict__ k_u, float4* __restrict__ pqc)
{
    const int idx = blockIdx.x * 256 + threadIdx.x;   // 0 .. B*S-1
    const int j   = idx & (SQ - 1);

    const float w0 = k_u[0], w1 = k_u[1];
    const float mk = 0.5f * (w0 * w0 + w1 * w1);

    const float qk0 = qk_v[0], qk1 = qk_v[1], qk2 = qk_v[2], qk3 = qk_v[3], qk4 = qk_v[4];
    const float vv0 = v_v[0],  vv1 = v_v[1],  vv2 = v_v[2],  vv3 = v_v[3],  vv4 = v_v[4];

    const float* xr = x + (size_t)idx * MDQ;
    const float x0 = xr[0], x1 = xr[1], x2 = xr[2], x3 = xr[3], x4 = xr[4];
    const float a  = x0*qk0 + x1*qk1 + x2*qk2 + x3*qk3 + x4*qk4;
    const float sv = x0*vv0 + x1*vv1 + x2*vv2 + x3*vv3 + x4*vv4;

    float sj, cj;
    __sincosf(freqs[j], &sj, &cj);
    const float mu = SCALEQ * a * rsqrtf(a * a * mk + EPSQ);   // rmsnorm(k) scalar
    pqc[idx] = make_float4(mu * cj, mu * sj, sv, 0.0f);
}

// ---------------- main kernel ----------------
#define BLOCK 256
#define RSETS 4             // waves per block
#define RPT 8               // rows per thread (register-blocked)
#define ROWSB (RSETS * RPT) // 32 rows per block
#define JITER (SQ / 64)     // 64 key iterations per thread
#define TILES (SQ / ROWSB)  // 128 tiles per batch -> grid 512

__global__ __launch_bounds__(BLOCK)
void ca_main(const float* __restrict__ x,
             const float* __restrict__ freqs,
             const float* __restrict__ qk_v,
             const float* __restrict__ o_v,
             const float* __restrict__ vproj_u,
             const float* __restrict__ q_u,
             const float* __restrict__ k_u,
             const float* __restrict__ o_u,
             const float4* __restrict__ pqc,
             float* __restrict__ out)
{
    const int tid = threadIdx.x;
    const int sp  = tid & 63;        // key-split lane within wave
    const int rs  = tid >> 6;        // wave index = row-set
    const int bx  = blockIdx.x;
    const int b   = bx / TILES;
    const int tile = bx % TILES;
    const int i0  = tile * ROWSB + rs * RPT;   // first row of this wave

    // ---- tiny shared params (broadcast loads) ----
    const float w0 = k_u[0], w1 = k_u[1];
    const float mk  = 0.5f * (w0 * w0 + w1 * w1);
    const float Mmu = SCALEQ * rsqrtf(mk);     // exact bound on |mu_j|

    const float qk0 = qk_v[0], qk1 = qk_v[1], qk2 = qk_v[2], qk3 = qk_v[3], qk4 = qk_v[4];
    const float u00 = q_u[0], u01 = q_u[1], u10 = q_u[2], u11 = q_u[3];
    const float m0 = 0.5f * (u00 * u00 + u01 * u01);
    const float m1 = 0.5f * (u10 * u10 + u11 * u11);
    const float A0 = u00 * w0 + u01 * w1, B0 = u01 * w0 - u00 * w1;
    const float A1 = u10 * w0 + u11 * w1, B1 = u11 * w0 - u10 * w1;

    // ---- per-row score coefficients, heads packed in .x/.y ----
    float2 al[RPT], be[RPT], Cc[RPT];
#pragma unroll
    for (int k = 0; k < RPT; ++k) {
        const int i = i0 + k;
        const float* xi = x + (size_t)(b * SQ + i) * MDQ;
        const float ai = xi[0]*qk0 + xi[1]*qk1 + xi[2]*qk2 + xi[3]*qk3 + xi[4]*qk4;
        float si, ci;
        __sincosf(freqs[i], &si, &ci);
        const float lam0 = SCALEQ * ai * rsqrtf(ai * ai * m0 + EPSQ);
        const float lam1 = SCALEQ * ai * rsqrtf(ai * ai * m1 + EPSQ);
        const float a0  = lam0 * (A0 * ci - B0 * si) * ISQ2;
        const float b0_ = lam0 * (A0 * si + B0 * ci) * ISQ2;
        const float a1  = lam1 * (A1 * ci - B1 * si) * ISQ2;
        const float b1_ = lam1 * (A1 * si + B1 * ci) * ISQ2;
        const float r0 = sqrtf(a0 * a0 + b0_ * b0_);
        const float r1 = sqrtf(a1 * a1 + b1_ * b1_);
        al[k] = make_float2(a0 * L2E, a1 * L2E);
        be[k] = make_float2(b0_ * L2E, b1_ * L2E);
        Cc[k] = make_float2(-r0 * Mmu * L2E, -r1 * Mmu * L2E);
    }

    // ---- single pass over keys: j = jj*64 + sp (coalesced 1KB/wave) ----
    const float4* __restrict__ p = pqc + (size_t)b * SQ + sp;
    float2 l[RPT], n[RPT];
#pragma unroll
    for (int k = 0; k < RPT; ++k) { l[k] = make_float2(0.f, 0.f); n[k] = make_float2(0.f, 0.f); }

#pragma unroll 4
    for (int jj = 0; jj < JITER; ++jj) {
        const float4 v = p[(size_t)jj * 64];
#pragma unroll
        for (int k = 0; k < RPT; ++k) {
            // packed over the two heads (.x / .y) -> v_pk_fma_f32
            float sx = fmaf(be[k].x, v.y, Cc[k].x);
            float sy = fmaf(be[k].y, v.y, Cc[k].y);
            sx = fmaf(al[k].x, v.x, sx);
            sy = fmaf(al[k].y, v.x, sy);
            const float ex = fast_exp2(sx);
            const float ey = fast_exp2(sy);
            l[k].x += ex;                      l[k].y += ey;
            n[k].x = fmaf(ex, v.z, n[k].x);    n[k].y = fmaf(ey, v.z, n[k].y);
        }
    }

    // ---- full-wave butterfly reduction (all 64 splits in this wave) ----
#pragma unroll
    for (int m = 1; m < 64; m <<= 1) {
#pragma unroll
        for (int k = 0; k < RPT; ++k) {
            l[k].x += __shfl_xor(l[k].x, m, 64);
            l[k].y += __shfl_xor(l[k].y, m, 64);
            n[k].x += __shfl_xor(n[k].x, m, 64);
            n[k].y += __shfl_xor(n[k].y, m, 64);
        }
    }

    // ---- epilogue: lanes 0..RPT-1 each write one row ----
    if (sp < RPT) {
        const int k = sp;
        const float L0 = fmaxf(l[k].x, 1e-30f);
        const float L1 = fmaxf(l[k].y, 1e-30f);
        const float W0 = n[k].x / L0, W1 = n[k].y / L1;

        const float p0 = vproj_u[0], p1 = vproj_u[1];
        const float d0 = p0 * o_v[0] + p1 * o_v[1];
        const float d1 = p0 * o_v[2] + p1 * o_v[3];
        const float so = W0 * d0 + W1 * d1;

        float* orow = out + (size_t)(b * SQ + i0 + k) * MDQ;
        orow[0] = so * o_u[0];
        orow[1] = so * o_u[1];
        orow[2] = so * o_u[2];
        orow[3] = so * o_u[3];
        orow[4] = so * o_u[4];
    }
}

// ---------------- fallback: single kernel, LDS-staged keys ----------------
#define FROWS 32
#define FSPLIT 8
#define FJSUB (SQ / FSPLIT)
#define FTILES (SQ / FROWS)

__global__ __launch_bounds__(256)
void ca_fallback(const float* __restrict__ x,
                 const float* __restrict__ freqs,
                 const float* __restrict__ qk_v,
                 const float* __restrict__ v_v,
                 const float* __restrict__ o_v,
                 const float* __restrict__ vproj_u,
                 const float* __restrict__ q_u,
                 const float* __restrict__ k_u,
                 const float* __restrict__ o_u,
                 float* __restrict__ out)
{
    __shared__ float2 sPQ[SQ];
    __shared__ float  sCv[SQ];
    __shared__ float4 sRed[FROWS][FSPLIT];

    const int tid  = threadIdx.x;
    const int b    = blockIdx.x / FTILES;
    const int tile = blockIdx.x % FTILES;

    const float w0 = k_u[0], w1 = k_u[1];
    const float mk  = 0.5f * (w0 * w0 + w1 * w1);
    const float Mmu = SCALEQ * rsqrtf(mk);

    const float qk0 = qk_v[0], qk1 = qk_v[1], qk2 = qk_v[2], qk3 = qk_v[3], qk4 = qk_v[4];
    const float vv0 = v_v[0],  vv1 = v_v[1],  vv2 = v_v[2],  vv3 = v_v[3],  vv4 = v_v[4];

    for (int k = 0; k < SQ / 256; ++k) {
        const int j = tid + k * 256;
        const float* xr = x + (size_t)(b * SQ + j) * MDQ;
        const float x0 = xr[0], x1 = xr[1], x2 = xr[2], x3 = xr[3], x4 = xr[4];
        const float a  = x0*qk0 + x1*qk1 + x2*qk2 + x3*qk3 + x4*qk4;
        const float sv = x0*vv0 + x1*vv1 + x2*vv2 + x3*vv3 + x4*vv4;
        float sj, cj;
        __sincosf(freqs[j], &sj, &cj);
        const float mu = SCALEQ * a * rsqrtf(a * a * mk + EPSQ);
        sPQ[j] = make_float2(mu * cj, mu * sj);
        sCv[j] = sv;
    }

    const int row = tid & (FROWS - 1);
    const int sp  = tid / FROWS;
    const int i   = tile * FROWS + row;

    const float u00 = q_u[0], u01 = q_u[1], u10 = q_u[2], u11 = q_u[3];
    const float m0 = 0.5f * (u00 * u00 + u01 * u01);
    const float m1 = 0.5f * (u10 * u10 + u11 * u11);
    const float A0 = u00 * w0 + u01 * w1, B0 = u01 * w0 - u00 * w1;
    const float A1 = u10 * w0 + u11 * w1, B1 = u11 * w0 - u10 * w1;

    const float* xi = x + (size_t)(b * SQ + i) * MDQ;
    const float ai = xi[0]*qk0 + xi[1]*qk1 + xi[2]*qk2 + xi[3]*qk3 + xi[4]*qk4;
    float si, ci;
    __sincosf(freqs[i], &si, &ci);
    const float lam0 = SCALEQ * ai * rsqrtf(ai * ai * m0 + EPSQ);
    const float lam1 = SCALEQ * ai * rsqrtf(ai * ai * m1 + EPSQ);
    const float alr0 = lam0 * (A0 * ci - B0 * si) * ISQ2;
    const float ber0 = lam0 * (A0 * si + B0 * ci) * ISQ2;
    const float alr1 = lam1 * (A1 * ci - B1 * si) * ISQ2;
    const float ber1 = lam1 * (A1 * si + B1 * ci) * ISQ2;
    const float r0 = sqrtf(alr0 * alr0 + ber0 * ber0);
    const float r1 = sqrtf(alr1 * alr1 + ber1 * ber1);
    const float al0 = alr0 * L2E, be0 = ber0 * L2E, C0 = -r0 * Mmu * L2E;
    const float al1 = alr1 * L2E, be1 = ber1 * L2E, C1 = -r1 * Mmu * L2E;

    __syncthreads();

    const float2* __restrict__ pq  = sPQ + sp * FJSUB;
    const float*  __restrict__ cvp = sCv + sp * FJSUB;
    float l0 = 0.f, n0 = 0.f, l1 = 0.f, n1 = 0.f;
#pragma unroll 8
    for (int jj = 0; jj < FJSUB; ++jj) {
        const float2 v = pq[jj];
        const float cv = cvp[jj];
        const float s0 = fmaf(al0, v.x, fmaf(be0, v.y, C0));
        const float s1 = fmaf(al1, v.x, fmaf(be1, v.y, C1));
        const float e0 = fast_exp2(s0);
        const float e1 = fast_exp2(s1);
        l0 += e0; n0 = fmaf(e0, cv, n0);
        l1 += e1; n1 = fmaf(e1, cv, n1);
    }

    sRed[row][sp] = make_float4(l0, n0, l1, n1);
    __syncthreads();

    if (tid < FROWS) {
        float L0 = 0.f, N0 = 0.f, L1 = 0.f, N1 = 0.f;
#pragma unroll
        for (int s = 0; s < FSPLIT; ++s) {
            const float4 t = sRed[tid][s];
            L0 += t.x; N0 += t.y; L1 += t.z; N1 += t.w;
        }
        L0 = fmaxf(L0, 1e-30f);
        L1 = fmaxf(L1, 1e-30f);
        const float W0 = N0 / L0, W1 = N1 / L1;
        const float p0 = vproj_u[0], p1 = vproj_u[1];
        const float d0 = p0 * o_v[0] + p1 * o_v[1];
        const float d1 = p0 * o_v[2] + p1 * o_v[3];
        const float so = W0 * d0 + W1 * d1;

        const int ig = tile * FROWS + tid;
        float* orow = out + (size_t)(b * SQ + ig) * MDQ;
        orow[0] = so * o_u[0];
        orow[1] = so * o_u[1];
        orow[2] = so * o_u[2];
        orow[3] = so * o_u[3];
        orow[4] = so * o_u[4];
    }
}

extern "C" void kernel_launch(void* const* d_in, const int* in_sizes, int n_in,
                              void* d_out, int out_size, void* d_ws, size_t ws_size,
                              hipStream_t stream) {
    (void)in_sizes; (void)n_in; (void)out_size;
    const float* x       = (const float*)d_in[0];
    const float* freqs   = (const float*)d_in[1];
    const float* qk_v    = (const float*)d_in[2];
    const float* v_v     = (const float*)d_in[3];
    const float* o_v     = (const float*)d_in[4];
    const float* vproj_u = (const float*)d_in[5];
    const float* q_u     = (const float*)d_in[6];
    const float* k_u     = (const float*)d_in[7];
    const float* o_u     = (const float*)d_in[8];
    float* out = (float*)d_out;

    const size_t pqc_bytes = (size_t)BQ * SQ * sizeof(float4);   // 256 KB
    if (ws_size >= pqc_bytes) {
        float4* pqc = (float4*)d_ws;
        hipLaunchKernelGGL(ca_prep, dim3(BQ * SQ / 256), dim3(256), 0, stream,
                           x, freqs, qk_v, v_v, k_u, pqc);
        hipLaunchKernelGGL(ca_main, dim3(BQ * TILES), dim3(BLOCK), 0, stream,
                           x, freqs, qk_v, o_v, vproj_u, q_u, k_u, o_u, pqc, out);
    } else {
        hipLaunchKernelGGL(ca_fallback, dim3(BQ * FTILES), dim3(256), 0, stream,
                           x, freqs, qk_v, v_v, o_v, vproj_u, q_u, k_u, o_u, out);
    }
}

// Round 5
// 97.996 us; speedup vs baseline: 1.2893x; 1.2893x over previous
//
#include <hip/hip_runtime.h>
#include <math.h>

// CompressedAttention: B=4,S=4096,H=2,KVH=1,D=2,MD=5
// scores_ij = al_{h,i}*P_j + be_{h,i}*Q_j (rank-2); v colinear -> scalar out weight.
// R5: revert to R3 register shape (RPT=4, no packing -- R4's RPT=8 spilled:
// WRITE_SIZE 8.5MB scratch, LDS 16K, 61us). Add block-cooperative double-buffered
// LDS staging of the key stream: each block reads each key ONCE (64MB total L2
// traffic vs R3's 268MB), inner loop reads keys from LDS (co-issues with VALU).

#define BQ 4
#define SQ 4096
#define MDQ 5
#define EPSQ 1e-6f
#define SCALEQ 16.0f
#define L2E 1.4426950408889634f
#define ISQ2 0.70710678118654752f

__device__ __forceinline__ float fast_exp2(float x) {
#if __has_builtin(__builtin_amdgcn_exp2f)
    return __builtin_amdgcn_exp2f(x);
#else
    return __expf(x * 0.6931471805599453f);
#endif
}

// ---------------- pre-pass: per-key scalars (P,Q,Cv) ----------------
__global__ __launch_bounds__(256)
void ca_prep(const float* __restrict__ x, const float* __restrict__ freqs,
             const float* __restrict__ qk_v, const float* __restrict__ v_v,
             const float* __restrict__ k_u, float4* __restrict__ pqc)
{
    const int idx = blockIdx.x * 256 + threadIdx.x;   // 0 .. B*S-1
    const int j   = idx & (SQ - 1);

    const float w0 = k_u[0], w1 = k_u[1];
    const float mk = 0.5f * (w0 * w0 + w1 * w1);

    const float qk0 = qk_v[0], qk1 = qk_v[1], qk2 = qk_v[2], qk3 = qk_v[3], qk4 = qk_v[4];
    const float vv0 = v_v[0],  vv1 = v_v[1],  vv2 = v_v[2],  vv3 = v_v[3],  vv4 = v_v[4];

    const float* xr = x + (size_t)idx * MDQ;
    const float x0 = xr[0], x1 = xr[1], x2 = xr[2], x3 = xr[3], x4 = xr[4];
    const float a  = x0*qk0 + x1*qk1 + x2*qk2 + x3*qk3 + x4*qk4;
    const float sv = x0*vv0 + x1*vv1 + x2*vv2 + x3*vv3 + x4*vv4;

    float sj, cj;
    __sincosf(freqs[j], &sj, &cj);
    const float mu = SCALEQ * a * rsqrtf(a * a * mk + EPSQ);   // rmsnorm(k) scalar
    pqc[idx] = make_float4(mu * cj, mu * sj, sv, 0.0f);
}

// ---------------- main kernel ----------------
#define BLOCK 256
#define RSETS 4             // waves per block
#define RPT 4               // rows per thread (R3-proven register footprint)
#define ROWSB (RSETS * RPT) // 16 rows per block
#define TILES (SQ / ROWSB)  // 256 tiles per batch -> grid 1024
#define KTILE 256           // keys staged per LDS tile
#define NKT (SQ / KTILE)    // 16 key tiles
#define JPT (KTILE / 64)    // 4 inner iterations per tile

__global__ __launch_bounds__(BLOCK)
void ca_main(const float* __restrict__ x,
             const float* __restrict__ freqs,
             const float* __restrict__ qk_v,
             const float* __restrict__ o_v,
             const float* __restrict__ vproj_u,
             const float* __restrict__ q_u,
             const float* __restrict__ k_u,
             const float* __restrict__ o_u,
             const float4* __restrict__ pqc,
             float* __restrict__ out)
{
    __shared__ float4 sKey[2][KTILE];    // 8 KB double buffer

    const int tid = threadIdx.x;
    const int sp  = tid & 63;        // key lane within wave
    const int rs  = tid >> 6;        // wave index = row-set
    const int bx  = blockIdx.x;
    const int b   = bx / TILES;
    const int tile = bx % TILES;
    const int i0  = tile * ROWSB + rs * RPT;   // first row of this wave

    // ---- tiny shared params (broadcast loads) ----
    const float w0 = k_u[0], w1 = k_u[1];
    const float mk  = 0.5f * (w0 * w0 + w1 * w1);
    const float Mmu = SCALEQ * rsqrtf(mk);     // exact bound on |mu_j|

    const float qk0 = qk_v[0], qk1 = qk_v[1], qk2 = qk_v[2], qk3 = qk_v[3], qk4 = qk_v[4];
    const float u00 = q_u[0], u01 = q_u[1], u10 = q_u[2], u11 = q_u[3];
    const float m0 = 0.5f * (u00 * u00 + u01 * u01);
    const float m1 = 0.5f * (u10 * u10 + u11 * u11);
    const float A0 = u00 * w0 + u01 * w1, B0 = u01 * w0 - u00 * w1;
    const float A1 = u10 * w0 + u11 * w1, B1 = u11 * w0 - u10 * w1;

    // ---- per-row score coefficients (4 rows, registers) ----
    float al0[RPT], be0[RPT], C0[RPT], al1[RPT], be1[RPT], C1[RPT];
#pragma unroll
    for (int k = 0; k < RPT; ++k) {
        const int i = i0 + k;
        const float* xi = x + (size_t)(b * SQ + i) * MDQ;
        const float ai = xi[0]*qk0 + xi[1]*qk1 + xi[2]*qk2 + xi[3]*qk3 + xi[4]*qk4;
        float si, ci;
        __sincosf(freqs[i], &si, &ci);
        const float lam0 = SCALEQ * ai * rsqrtf(ai * ai * m0 + EPSQ);
        const float lam1 = SCALEQ * ai * rsqrtf(ai * ai * m1 + EPSQ);
        const float a0  = lam0 * (A0 * ci - B0 * si) * ISQ2;
        const float b0_ = lam0 * (A0 * si + B0 * ci) * ISQ2;
        const float a1  = lam1 * (A1 * ci - B1 * si) * ISQ2;
        const float b1_ = lam1 * (A1 * si + B1 * ci) * ISQ2;
        const float r0 = sqrtf(a0 * a0 + b0_ * b0_);
        const float r1 = sqrtf(a1 * a1 + b1_ * b1_);
        al0[k] = a0 * L2E;  be0[k] = b0_ * L2E;  C0[k] = -r0 * Mmu * L2E;
        al1[k] = a1 * L2E;  be1[k] = b1_ * L2E;  C1[k] = -r1 * Mmu * L2E;
    }

    // ---- key loop: block-cooperative double-buffered LDS staging ----
    const float4* __restrict__ gsrc = pqc + (size_t)b * SQ + tid;  // this thread's slot

    float4 stage = gsrc[0];          // prefetch tile 0
    sKey[0][tid] = stage;
    __syncthreads();

    float l0[RPT], n0[RPT], l1[RPT], n1[RPT];
#pragma unroll
    for (int k = 0; k < RPT; ++k) { l0[k] = 0.f; n0[k] = 0.f; l1[k] = 0.f; n1[k] = 0.f; }

#pragma unroll 2
    for (int t = 0; t < NKT; ++t) {
        const int cur = t & 1;
        if (t + 1 < NKT) stage = gsrc[(size_t)(t + 1) * KTILE];   // overlap with compute

        const float4* kb = &sKey[cur][sp];
#pragma unroll
        for (int jj = 0; jj < JPT; ++jj) {
            const float4 v = kb[jj * 64];
#pragma unroll
            for (int k = 0; k < RPT; ++k) {
                const float s0 = fmaf(al0[k], v.x, fmaf(be0[k], v.y, C0[k]));
                const float s1 = fmaf(al1[k], v.x, fmaf(be1[k], v.y, C1[k]));
                const float e0 = fast_exp2(s0);
                const float e1 = fast_exp2(s1);
                l0[k] += e0;  n0[k] = fmaf(e0, v.z, n0[k]);
                l1[k] += e1;  n1[k] = fmaf(e1, v.z, n1[k]);
            }
        }

        if (t + 1 < NKT) {
            sKey[cur ^ 1][tid] = stage;
            __syncthreads();
        }
    }

    // ---- full-wave butterfly reduction (all 64 splits in this wave) ----
#pragma unroll
    for (int m = 1; m < 64; m <<= 1) {
#pragma unroll
        for (int k = 0; k < RPT; ++k) {
            l0[k] += __shfl_xor(l0[k], m, 64);
            n0[k] += __shfl_xor(n0[k], m, 64);
            l1[k] += __shfl_xor(l1[k], m, 64);
            n1[k] += __shfl_xor(n1[k], m, 64);
        }
    }

    // ---- epilogue: lanes 0..RPT-1 each write one row ----
    if (sp < RPT) {
        const int k = sp;
        const float L0 = fmaxf(l0[k], 1e-30f);
        const float L1 = fmaxf(l1[k], 1e-30f);
        const float W0 = n0[k] / L0, W1 = n1[k] / L1;

        const float p0 = vproj_u[0], p1 = vproj_u[1];
        const float d0 = p0 * o_v[0] + p1 * o_v[1];
        const float d1 = p0 * o_v[2] + p1 * o_v[3];
        const float so = W0 * d0 + W1 * d1;

        float* orow = out + (size_t)(b * SQ + i0 + k) * MDQ;
        orow[0] = so * o_u[0];
        orow[1] = so * o_u[1];
        orow[2] = so * o_u[2];
        orow[3] = so * o_u[3];
        orow[4] = so * o_u[4];
    }
}

// ---------------- fallback: single kernel, LDS-staged keys ----------------
#define FROWS 32
#define FSPLIT 8
#define FJSUB (SQ / FSPLIT)
#define FTILES (SQ / FROWS)

__global__ __launch_bounds__(256)
void ca_fallback(const float* __restrict__ x,
                 const float* __restrict__ freqs,
                 const float* __restrict__ qk_v,
                 const float* __restrict__ v_v,
                 const float* __restrict__ o_v,
                 const float* __restrict__ vproj_u,
                 const float* __restrict__ q_u,
                 const float* __restrict__ k_u,
                 const float* __restrict__ o_u,
                 float* __restrict__ out)
{
    __shared__ float2 sPQ[SQ];
    __shared__ float  sCv[SQ];
    __shared__ float4 sRed[FROWS][FSPLIT];

    const int tid  = threadIdx.x;
    const int b    = blockIdx.x / FTILES;
    const int tile = blockIdx.x % FTILES;

    const float w0 = k_u[0], w1 = k_u[1];
    const float mk  = 0.5f * (w0 * w0 + w1 * w1);
    const float Mmu = SCALEQ * rsqrtf(mk);

    const float qk0 = qk_v[0], qk1 = qk_v[1], qk2 = qk_v[2], qk3 = qk_v[3], qk4 = qk_v[4];
    const float vv0 = v_v[0],  vv1 = v_v[1],  vv2 = v_v[2],  vv3 = v_v[3],  vv4 = v_v[4];

    for (int k = 0; k < SQ / 256; ++k) {
        const int j = tid + k * 256;
        const float* xr = x + (size_t)(b * SQ + j) * MDQ;
        const float x0 = xr[0], x1 = xr[1], x2 = xr[2], x3 = xr[3], x4 = xr[4];
        const float a  = x0*qk0 + x1*qk1 + x2*qk2 + x3*qk3 + x4*qk4;
        const float sv = x0*vv0 + x1*vv1 + x2*vv2 + x3*vv3 + x4*vv4;
        float sj, cj;
        __sincosf(freqs[j], &sj, &cj);
        const float mu = SCALEQ * a * rsqrtf(a * a * mk + EPSQ);
        sPQ[j] = make_float2(mu * cj, mu * sj);
        sCv[j] = sv;
    }

    const int row = tid & (FROWS - 1);
    const int sp  = tid / FROWS;
    const int i   = tile * FROWS + row;

    const float u00 = q_u[0], u01 = q_u[1], u10 = q_u[2], u11 = q_u[3];
    const float m0 = 0.5f * (u00 * u00 + u01 * u01);
    const float m1 = 0.5f * (u10 * u10 + u11 * u11);
    const float A0 = u00 * w0 + u01 * w1, B0 = u01 * w0 - u00 * w1;
    const float A1 = u10 * w0 + u11 * w1, B1 = u11 * w0 - u10 * w1;

    const float* xi = x + (size_t)(b * SQ + i) * MDQ;
    const float ai = xi[0]*qk0 + xi[1]*qk1 + xi[2]*qk2 + xi[3]*qk3 + xi[4]*qk4;
    float si, ci;
    __sincosf(freqs[i], &si, &ci);
    const float lam0 = SCALEQ * ai * rsqrtf(ai * ai * m0 + EPSQ);
    const float lam1 = SCALEQ * ai * rsqrtf(ai * ai * m1 + EPSQ);
    const float alr0 = lam0 * (A0 * ci - B0 * si) * ISQ2;
    const float ber0 = lam0 * (A0 * si + B0 * ci) * ISQ2;
    const float alr1 = lam1 * (A1 * ci - B1 * si) * ISQ2;
    const float ber1 = lam1 * (A1 * si + B1 * ci) * ISQ2;
    const float r0 = sqrtf(alr0 * alr0 + ber0 * ber0);
    const float r1 = sqrtf(alr1 * alr1 + ber1 * ber1);
    const float al0 = alr0 * L2E, be0 = ber0 * L2E, C0 = -r0 * Mmu * L2E;
    const float al1 = alr1 * L2E, be1 = ber1 * L2E, C1 = -r1 * Mmu * L2E;

    __syncthreads();

    const float2* __restrict__ pq  = sPQ + sp * FJSUB;
    const float*  __restrict__ cvp = sCv + sp * FJSUB;
    float l0 = 0.f, n0 = 0.f, l1 = 0.f, n1 = 0.f;
#pragma unroll 8
    for (int jj = 0; jj < FJSUB; ++jj) {
        const float2 v = pq[jj];
        const float cv = cvp[jj];
        const float s0 = fmaf(al0, v.x, fmaf(be0, v.y, C0));
        const float s1 = fmaf(al1, v.x, fmaf(be1, v.y, C1));
        const float e0 = fast_exp2(s0);
        const float e1 = fast_exp2(s1);
        l0 += e0; n0 = fmaf(e0, cv, n0);
        l1 += e1; n1 = fmaf(e1, cv, n1);
    }

    sRed[row][sp] = make_float4(l0, n0, l1, n1);
    __syncthreads();

    if (tid < FROWS) {
        float L0 = 0.f, N0 = 0.f, L1 = 0.f, N1 = 0.f;
#pragma unroll
        for (int s = 0; s < FSPLIT; ++s) {
            const float4 t = sRed[tid][s];
            L0 += t.x; N0 += t.y; L1 += t.z; N1 += t.w;
        }
        L0 = fmaxf(L0, 1e-30f);
        L1 = fmaxf(L1, 1e-30f);
        const float W0 = N0 / L0, W1 = N1 / L1;
        const float p0 = vproj_u[0], p1 = vproj_u[1];
        const float d0 = p0 * o_v[0] + p1 * o_v[1];
        const float d1 = p0 * o_v[2] + p1 * o_v[3];
        const float so = W0 * d0 + W1 * d1;

        const int ig = tile * FROWS + tid;
        float* orow = out + (size_t)(b * SQ + ig) * MDQ;
        orow[0] = so * o_u[0];
        orow[1] = so * o_u[1];
        orow[2] = so * o_u[2];
        orow[3] = so * o_u[3];
        orow[4] = so * o_u[4];
    }
}

extern "C" void kernel_launch(void* const* d_in, const int* in_sizes, int n_in,
                              void* d_out, int out_size, void* d_ws, size_t ws_size,
                              hipStream_t stream) {
    (void)in_sizes; (void)n_in; (void)out_size;
    const float* x       = (const float*)d_in[0];
    const float* freqs   = (const float*)d_in[1];
    const float* qk_v    = (const float*)d_in[2];
    const float* v_v     = (const float*)d_in[3];
    const float* o_v     = (const float*)d_in[4];
    const float* vproj_u = (const float*)d_in[5];
    const float* q_u     = (const float*)d_in[6];
    const float* k_u     = (const float*)d_in[7];
    const float* o_u     = (const float*)d_in[8];
    float* out = (float*)d_out;

    const size_t pqc_bytes = (size_t)BQ * SQ * sizeof(float4);   // 256 KB
    if (ws_size >= pqc_bytes) {
        float4* pqc = (float4*)d_ws;
        hipLaunchKernelGGL(ca_prep, dim3(BQ * SQ / 256), dim3(256), 0, stream,
                           x, freqs, qk_v, v_v, k_u, pqc);
        hipLaunchKernelGGL(ca_main, dim3(BQ * TILES), dim3(BLOCK), 0, stream,
                           x, freqs, qk_v, o_v, vproj_u, q_u, k_u, o_u, pqc, out);
    } else {
        hipLaunchKernelGGL(ca_fallback, dim3(BQ * FTILES), dim3(256), 0, stream,
                           x, freqs, qk_v, v_v, o_v, vproj_u, q_u, k_u, o_u, out);
    }
}

// Round 6
// 92.920 us; speedup vs baseline: 1.3597x; 1.0546x over previous
//
#include <hip/hip_runtime.h>
#include <math.h>

// CompressedAttention: B=4,S=4096,H=2,KVH=1,D=2,MD=5
// scores_ij = al_{h,i}*P_j + be_{h,i}*Q_j (rank-2); v colinear -> scalar out weight.
// R6: packed-fp32 math (v_pk_fma via ext_vector float2, heads in lanes .x/.y),
// RPT=2 + grid 2048 -> 8 blocks/CU, 8 waves/SIMD (VGPR ~45, no spill),
// LDS double-buffered key staging (required: direct-L2 at this wave count
// would need 512MB ~ >L2 ceiling). Single barrier per 256-key tile.

#define BQ 4
#define SQ 4096
#define MDQ 5
#define EPSQ 1e-6f
#define SCALEQ 16.0f
#define L2E 1.4426950408889634f
#define ISQ2 0.70710678118654752f

typedef float v2f __attribute__((ext_vector_type(2)));

__device__ __forceinline__ float fast_exp2(float x) {
#if __has_builtin(__builtin_amdgcn_exp2f)
    return __builtin_amdgcn_exp2f(x);
#else
    return __expf(x * 0.6931471805599453f);
#endif
}

// ---------------- pre-pass: per-key scalars (P,Q,Cv,Cv) ----------------
__global__ __launch_bounds__(256)
void ca_prep(const float* __restrict__ x, const float* __restrict__ freqs,
             const float* __restrict__ qk_v, const float* __restrict__ v_v,
             const float* __restrict__ k_u, float4* __restrict__ pqc)
{
    const int idx = blockIdx.x * 256 + threadIdx.x;   // 0 .. B*S-1
    const int j   = idx & (SQ - 1);

    const float w0 = k_u[0], w1 = k_u[1];
    const float mk = 0.5f * (w0 * w0 + w1 * w1);

    const float qk0 = qk_v[0], qk1 = qk_v[1], qk2 = qk_v[2], qk3 = qk_v[3], qk4 = qk_v[4];
    const float vv0 = v_v[0],  vv1 = v_v[1],  vv2 = v_v[2],  vv3 = v_v[3],  vv4 = v_v[4];

    const float* xr = x + (size_t)idx * MDQ;
    const float x0 = xr[0], x1 = xr[1], x2 = xr[2], x3 = xr[3], x4 = xr[4];
    const float a  = x0*qk0 + x1*qk1 + x2*qk2 + x3*qk3 + x4*qk4;
    const float sv = x0*vv0 + x1*vv1 + x2*vv2 + x3*vv3 + x4*vv4;

    float sj, cj;
    __sincosf(freqs[j], &sj, &cj);
    const float mu = SCALEQ * a * rsqrtf(a * a * mk + EPSQ);   // rmsnorm(k) scalar
    pqc[idx] = make_float4(mu * cj, mu * sj, sv, sv);          // Cv duplicated in .w
}

// ---------------- main kernel ----------------
#define BLOCK 256
#define RSETS 4             // waves per block
#define RPT 2               // rows per thread (small state -> 8 waves/SIMD)
#define ROWSB (RSETS * RPT) // 8 rows per block
#define TILES (SQ / ROWSB)  // 512 tiles per batch -> grid 2048 (8 blocks/CU)
#define KTILE 256           // keys staged per LDS tile
#define NKT (SQ / KTILE)    // 16 key tiles
#define JPT (KTILE / 64)    // 4 inner iterations per tile

__global__ __launch_bounds__(BLOCK)
void ca_main(const float* __restrict__ x,
             const float* __restrict__ freqs,
             const float* __restrict__ qk_v,
             const float* __restrict__ o_v,
             const float* __restrict__ vproj_u,
             const float* __restrict__ q_u,
             const float* __restrict__ k_u,
             const float* __restrict__ o_u,
             const float4* __restrict__ pqc,
             float* __restrict__ out)
{
    __shared__ float4 sKey[2][KTILE];    // 8 KB double buffer

    const int tid = threadIdx.x;
    const int sp  = tid & 63;        // key lane within wave
    const int rs  = tid >> 6;        // wave index = row-set
    const int bx  = blockIdx.x;
    const int b   = bx / TILES;
    const int tile = bx % TILES;
    const int i0  = tile * ROWSB + rs * RPT;   // first row of this wave

    // ---- tiny shared params (broadcast / scalar loads) ----
    const float w0 = k_u[0], w1 = k_u[1];
    const float mk  = 0.5f * (w0 * w0 + w1 * w1);
    const float Mmu = SCALEQ * rsqrtf(mk);     // exact bound on |mu_j|

    const float qk0 = qk_v[0], qk1 = qk_v[1], qk2 = qk_v[2], qk3 = qk_v[3], qk4 = qk_v[4];
    const float u00 = q_u[0], u01 = q_u[1], u10 = q_u[2], u11 = q_u[3];
    const float m0 = 0.5f * (u00 * u00 + u01 * u01);
    const float m1 = 0.5f * (u10 * u10 + u11 * u11);
    const float A0 = u00 * w0 + u01 * w1, B0 = u01 * w0 - u00 * w1;
    const float A1 = u10 * w0 + u11 * w1, B1 = u11 * w0 - u10 * w1;

    // ---- per-row score coefficients, heads packed in v2f lanes ----
    v2f al[RPT], be[RPT], Cc[RPT];
#pragma unroll
    for (int k = 0; k < RPT; ++k) {
        const int i = i0 + k;
        const float* xi = x + (size_t)(b * SQ + i) * MDQ;
        const float ai = xi[0]*qk0 + xi[1]*qk1 + xi[2]*qk2 + xi[3]*qk3 + xi[4]*qk4;
        float si, ci;
        __sincosf(freqs[i], &si, &ci);
        const float lam0 = SCALEQ * ai * rsqrtf(ai * ai * m0 + EPSQ);
        const float lam1 = SCALEQ * ai * rsqrtf(ai * ai * m1 + EPSQ);
        const float a0  = lam0 * (A0 * ci - B0 * si) * ISQ2;
        const float b0_ = lam0 * (A0 * si + B0 * ci) * ISQ2;
        const float a1  = lam1 * (A1 * ci - B1 * si) * ISQ2;
        const float b1_ = lam1 * (A1 * si + B1 * ci) * ISQ2;
        const float r0 = sqrtf(a0 * a0 + b0_ * b0_);
        const float r1 = sqrtf(a1 * a1 + b1_ * b1_);
        al[k] = (v2f){a0 * L2E, a1 * L2E};
        be[k] = (v2f){b0_ * L2E, b1_ * L2E};
        Cc[k] = (v2f){-r0 * Mmu * L2E, -r1 * Mmu * L2E};
    }

    // ---- key loop: block-cooperative double-buffered LDS staging ----
    const float4* __restrict__ gsrc = pqc + (size_t)b * SQ + tid;

    float4 stage = gsrc[0];          // prefetch tile 0
    sKey[0][tid] = stage;
    __syncthreads();

    v2f l[RPT], n[RPT];
#pragma unroll
    for (int k = 0; k < RPT; ++k) { l[k] = (v2f){0.f, 0.f}; n[k] = (v2f){0.f, 0.f}; }

    for (int t = 0; t < NKT; ++t) {
        const int cur = t & 1;
        if (t + 1 < NKT) stage = gsrc[(size_t)(t + 1) * KTILE];   // overlap with compute

        const float4* kb = &sKey[cur][sp];
#pragma unroll
        for (int jj = 0; jj < JPT; ++jj) {
            const float4 v = kb[jj * 64];
            const v2f vx = (v2f){v.x, v.x};
            const v2f vy = (v2f){v.y, v.y};
            const v2f vz = (v2f){v.z, v.w};      // Cv duplicated by prep
#pragma unroll
            for (int k = 0; k < RPT; ++k) {
                const v2f s = al[k] * vx + (be[k] * vy + Cc[k]);   // 2x v_pk_fma
                v2f e;
                e.x = fast_exp2(s.x);
                e.y = fast_exp2(s.y);
                l[k] += e;                        // v_pk_add
                n[k] += e * vz;                   // v_pk_fma
            }
        }

        if (t + 1 < NKT) {
            sKey[cur ^ 1][tid] = stage;
            __syncthreads();
        }
    }

    // ---- full-wave butterfly reduction (all 64 splits in this wave) ----
#pragma unroll
    for (int m = 1; m < 64; m <<= 1) {
#pragma unroll
        for (int k = 0; k < RPT; ++k) {
            l[k].x += __shfl_xor(l[k].x, m, 64);
            l[k].y += __shfl_xor(l[k].y, m, 64);
            n[k].x += __shfl_xor(n[k].x, m, 64);
            n[k].y += __shfl_xor(n[k].y, m, 64);
        }
    }

    // ---- epilogue: lanes 0..RPT-1 each write one row ----
    if (sp < RPT) {
        const int k = sp;
        const float L0 = fmaxf(l[k].x, 1e-30f);
        const float L1 = fmaxf(l[k].y, 1e-30f);
        const float W0 = n[k].x / L0, W1 = n[k].y / L1;

        const float p0 = vproj_u[0], p1 = vproj_u[1];
        const float d0 = p0 * o_v[0] + p1 * o_v[1];
        const float d1 = p0 * o_v[2] + p1 * o_v[3];
        const float so = W0 * d0 + W1 * d1;

        float* orow = out + (size_t)(b * SQ + i0 + k) * MDQ;
        orow[0] = so * o_u[0];
        orow[1] = so * o_u[1];
        orow[2] = so * o_u[2];
        orow[3] = so * o_u[3];
        orow[4] = so * o_u[4];
    }
}

// ---------------- fallback: single kernel, LDS-staged keys ----------------
#define FROWS 32
#define FSPLIT 8
#define FJSUB (SQ / FSPLIT)
#define FTILES (SQ / FROWS)

__global__ __launch_bounds__(256)
void ca_fallback(const float* __restrict__ x,
                 const float* __restrict__ freqs,
                 const float* __restrict__ qk_v,
                 const float* __restrict__ v_v,
                 const float* __restrict__ o_v,
                 const float* __restrict__ vproj_u,
                 const float* __restrict__ q_u,
                 const float* __restrict__ k_u,
                 const float* __restrict__ o_u,
                 float* __restrict__ out)
{
    __shared__ float2 sPQ[SQ];
    __shared__ float  sCv[SQ];
    __shared__ float4 sRed[FROWS][FSPLIT];

    const int tid  = threadIdx.x;
    const int b    = blockIdx.x / FTILES;
    const int tile = blockIdx.x % FTILES;

    const float w0 = k_u[0], w1 = k_u[1];
    const float mk  = 0.5f * (w0 * w0 + w1 * w1);
    const float Mmu = SCALEQ * rsqrtf(mk);

    const float qk0 = qk_v[0], qk1 = qk_v[1], qk2 = qk_v[2], qk3 = qk_v[3], qk4 = qk_v[4];
    const float vv0 = v_v[0],  vv1 = v_v[1],  vv2 = v_v[2],  vv3 = v_v[3],  vv4 = v_v[4];

    for (int k = 0; k < SQ / 256; ++k) {
        const int j = tid + k * 256;
        const float* xr = x + (size_t)(b * SQ + j) * MDQ;
        const float x0 = xr[0], x1 = xr[1], x2 = xr[2], x3 = xr[3], x4 = xr[4];
        const float a  = x0*qk0 + x1*qk1 + x2*qk2 + x3*qk3 + x4*qk4;
        const float sv = x0*vv0 + x1*vv1 + x2*vv2 + x3*vv3 + x4*vv4;
        float sj, cj;
        __sincosf(freqs[j], &sj, &cj);
        const float mu = SCALEQ * a * rsqrtf(a * a * mk + EPSQ);
        sPQ[j] = make_float2(mu * cj, mu * sj);
        sCv[j] = sv;
    }

    const int row = tid & (FROWS - 1);
    const int sp  = tid / FROWS;
    const int i   = tile * FROWS + row;

    const float u00 = q_u[0], u01 = q_u[1], u10 = q_u[2], u11 = q_u[3];
    const float m0 = 0.5f * (u00 * u00 + u01 * u01);
    const float m1 = 0.5f * (u10 * u10 + u11 * u11);
    const float A0 = u00 * w0 + u01 * w1, B0 = u01 * w0 - u00 * w1;
    const float A1 = u10 * w0 + u11 * w1, B1 = u11 * w0 - u10 * w1;

    const float* xi = x + (size_t)(b * SQ + i) * MDQ;
    const float ai = xi[0]*qk0 + xi[1]*qk1 + xi[2]*qk2 + xi[3]*qk3 + xi[4]*qk4;
    float si, ci;
    __sincosf(freqs[i], &si, &ci);
    const float lam0 = SCALEQ * ai * rsqrtf(ai * ai * m0 + EPSQ);
    const float lam1 = SCALEQ * ai * rsqrtf(ai * ai * m1 + EPSQ);
    const float alr0 = lam0 * (A0 * ci - B0 * si) * ISQ2;
    const float ber0 = lam0 * (A0 * si + B0 * ci) * ISQ2;
    const float alr1 = lam1 * (A1 * ci - B1 * si) * ISQ2;
    const float ber1 = lam1 * (A1 * si + B1 * ci) * ISQ2;
    const float r0 = sqrtf(alr0 * alr0 + ber0 * ber0);
    const float r1 = sqrtf(alr1 * alr1 + ber1 * ber1);
    const float al0 = alr0 * L2E, be0 = ber0 * L2E, C0 = -r0 * Mmu * L2E;
    const float al1 = alr1 * L2E, be1 = ber1 * L2E, C1 = -r1 * Mmu * L2E;

    __syncthreads();

    const float2* __restrict__ pq  = sPQ + sp * FJSUB;
    const float*  __restrict__ cvp = sCv + sp * FJSUB;
    float l0 = 0.f, n0 = 0.f, l1 = 0.f, n1 = 0.f;
#pragma unroll 8
    for (int jj = 0; jj < FJSUB; ++jj) {
        const float2 v = pq[jj];
        const float cv = cvp[jj];
        const float s0 = fmaf(al0, v.x, fmaf(be0, v.y, C0));
        const float s1 = fmaf(al1, v.x, fmaf(be1, v.y, C1));
        const float e0 = fast_exp2(s0);
        const float e1 = fast_exp2(s1);
        l0 += e0; n0 = fmaf(e0, cv, n0);
        l1 += e1; n1 = fmaf(e1, cv, n1);
    }

    sRed[row][sp] = make_float4(l0, n0, l1, n1);
    __syncthreads();

    if (tid < FROWS) {
        float L0 = 0.f, N0 = 0.f, L1 = 0.f, N1 = 0.f;
#pragma unroll
        for (int s = 0; s < FSPLIT; ++s) {
            const float4 t = sRed[tid][s];
            L0 += t.x; N0 += t.y; L1 += t.z; N1 += t.w;
        }
        L0 = fmaxf(L0, 1e-30f);
        L1 = fmaxf(L1, 1e-30f);
        const float W0 = N0 / L0, W1 = N1 / L1;
        const float p0 = vproj_u[0], p1 = vproj_u[1];
        const float d0 = p0 * o_v[0] + p1 * o_v[1];
        const float d1 = p0 * o_v[2] + p1 * o_v[3];
        const float so = W0 * d0 + W1 * d1;

        const int ig = tile * FROWS + tid;
        float* orow = out + (size_t)(b * SQ + ig) * MDQ;
        orow[0] = so * o_u[0];
        orow[1] = so * o_u[1];
        orow[2] = so * o_u[2];
        orow[3] = so * o_u[3];
        orow[4] = so * o_u[4];
    }
}

extern "C" void kernel_launch(void* const* d_in, const int* in_sizes, int n_in,
                              void* d_out, int out_size, void* d_ws, size_t ws_size,
                              hipStream_t stream) {
    (void)in_sizes; (void)n_in; (void)out_size;
    const float* x       = (const float*)d_in[0];
    const float* freqs   = (const float*)d_in[1];
    const float* qk_v    = (const float*)d_in[2];
    const float* v_v     = (const float*)d_in[3];
    const float* o_v     = (const float*)d_in[4];
    const float* vproj_u = (const float*)d_in[5];
    const float* q_u     = (const float*)d_in[6];
    const float* k_u     = (const float*)d_in[7];
    const float* o_u     = (const float*)d_in[8];
    float* out = (float*)d_out;

    const size_t pqc_bytes = (size_t)BQ * SQ * sizeof(float4);   // 256 KB
    if (ws_size >= pqc_bytes) {
        float4* pqc = (float4*)d_ws;
        hipLaunchKernelGGL(ca_prep, dim3(BQ * SQ / 256), dim3(256), 0, stream,
                           x, freqs, qk_v, v_v, k_u, pqc);
        hipLaunchKernelGGL(ca_main, dim3(BQ * TILES), dim3(BLOCK), 0, stream,
                           x, freqs, qk_v, o_v, vproj_u, q_u, k_u, o_u, pqc, out);
    } else {
        hipLaunchKernelGGL(ca_fallback, dim3(BQ * FTILES), dim3(256), 0, stream,
                           x, freqs, qk_v, v_v, o_v, vproj_u, q_u, k_u, o_u, out);
    }
}